// Round 9
// baseline (234.126 us; speedup 1.0000x reference)
//
#include <hip/hip_runtime.h>

#define KF 8
#define TN 4
#define SDIM 16
#define EMB 128
#define NS 8     // rel-pass split factor
#define NB 128   // rel-scatter chunk count
#define NT 512   // tail-scatter blocks
#define NRMAX 512
#define SCE 1024 // elements per scan block

typedef unsigned int u32;

// ---- bf16 helpers (manual RNE pack, bit-shift unpack) ----
__device__ __forceinline__ u32 pack2bf(float a, float b) {
    u32 ua = __float_as_uint(a), ub = __float_as_uint(b);
    ua = (ua + 0x7FFFu + ((ua >> 16) & 1u)) >> 16;
    ub = (ub + 0x7FFFu + ((ub >> 16) & 1u)) >> 16;
    return ua | (ub << 16);
}
__device__ __forceinline__ float lo16(u32 w) { return __uint_as_float(w << 16); }
__device__ __forceinline__ float hi16(u32 w) { return __uint_as_float(w & 0xFFFF0000u); }

// ---------------- init: zero deg, rcnt, rsumA, rsumB in one dispatch ----------------
__global__ __launch_bounds__(256) void k_init(int* __restrict__ deg, int num_ent,
                                              int* __restrict__ rcnt, int num_rel,
                                              float* __restrict__ rsumA, float* __restrict__ rsumB,
                                              int nrsum) {
    int i = blockIdx.x * 256 + threadIdx.x;
    if (i < num_ent) deg[i] = 0;
    if (i < num_rel) rcnt[i] = 0;
    if (i < nrsum) { rsumA[i] = 0.f; rsumB[i] = 0.f; }
}

// ---------------- histograms ----------------
__global__ __launch_bounds__(256) void k_hist(const int* __restrict__ tails, const int* __restrict__ types,
                                              int nE, int num_rel,
                                              int* __restrict__ deg, int* __restrict__ rcnt) {
    __shared__ int hist[NRMAX];
    for (int q = threadIdx.x; q < num_rel; q += 256) hist[q] = 0;
    __syncthreads();
    for (int i = blockIdx.x * 256 + threadIdx.x; i < nE; i += gridDim.x * 256) {
        atomicAdd(&deg[tails[i]], 1);
        atomicAdd(&hist[types[i]], 1);
    }
    __syncthreads();
    for (int q = threadIdx.x; q < num_rel; q += 256) {
        int h = hist[q];
        if (h) atomicAdd(&rcnt[q], h);
    }
}

// ---------------- small exclusive scan as device func (one block) ----------------
__device__ void scan_small(const int* __restrict__ in, int* __restrict__ out, int* __restrict__ out2, int n) {
    __shared__ int warp_sums[16];
    int carry = 0;
    int lane = threadIdx.x & 63, wid = threadIdx.x >> 6;
    int nw = blockDim.x >> 6;
    for (int base = 0; base < n; base += blockDim.x) {
        int i = base + (int)threadIdx.x;
        int v = (i < n) ? in[i] : 0;
        int sv = v;
        for (int o = 1; o < 64; o <<= 1) { int t = __shfl_up(sv, o, 64); if (lane >= o) sv += t; }
        if (lane == 63) warp_sums[wid] = sv;
        __syncthreads();
        if (wid == 0 && lane < nw) {
            int ws = warp_sums[lane];
            for (int o = 1; o < 16; o <<= 1) { int t = __shfl_up(ws, o, 64); if (lane >= o) ws += t; }
            warp_sums[lane] = ws;
        }
        __syncthreads();
        int wofs = (wid > 0) ? warp_sums[wid - 1] : 0;
        int total = warp_sums[nw - 1];
        if (i < n) {
            int e = carry + wofs + sv - v;
            out[i] = e;
            if (out2) out2[i] = e;
        }
        carry += total;
        __syncthreads();
    }
    if (threadIdx.x == 0) out[n] = carry;
}

// block 0: bsum->bofs ; block 1: rcnt->rel_off(+rel_cur)
__global__ void k_scan_pair(const int* __restrict__ bsum, int* __restrict__ bofs, int nblk,
                            const int* __restrict__ rcnt, int* __restrict__ rel_off,
                            int* __restrict__ rel_cur, int num_rel) {
    if (blockIdx.x == 0) scan_small(bsum, bofs, nullptr, nblk);
    else                 scan_small(rcnt, rel_off, rel_cur, num_rel);
}

// ---------------- hierarchical scan phase 1 ----------------
__global__ __launch_bounds__(256) void k_scan1(const int* __restrict__ in, int* __restrict__ out,
                                               int* __restrict__ bsum, int n) {
    __shared__ int warp_sums[4];
    int blk = blockIdx.x;
    int i0 = blk * SCE + (int)threadIdx.x * 4;
    int v[4];
#pragma unroll
    for (int j = 0; j < 4; ++j) { int i = i0 + j; v[j] = (i < n) ? in[i] : 0; }
    int tsum = v[0] + v[1] + v[2] + v[3];
    int lane = threadIdx.x & 63, wid = threadIdx.x >> 6;
    int sv = tsum;
    for (int o = 1; o < 64; o <<= 1) { int t = __shfl_up(sv, o, 64); if (lane >= o) sv += t; }
    if (lane == 63) warp_sums[wid] = sv;
    __syncthreads();
    if (threadIdx.x == 0) {
        int s = 0;
        for (int w = 0; w < 4; ++w) { int t = warp_sums[w]; warp_sums[w] = s; s += t; }
        bsum[blk] = s;
    }
    __syncthreads();
    int run = warp_sums[wid] + sv - tsum;
#pragma unroll
    for (int j = 0; j < 4; ++j) { int i = i0 + j; if (i < n) out[i] = run; run += v[j]; }
}

// ---------------- hierarchical scan phase 3 ----------------
__global__ __launch_bounds__(256) void k_scan2(int* __restrict__ out, int* __restrict__ out2,
                                               const int* __restrict__ bofs, int n, int nblk) {
    int blk = blockIdx.x;
    int add = bofs[blk];
    int i0 = blk * SCE + (int)threadIdx.x * 4;
#pragma unroll
    for (int j = 0; j < 4; ++j) {
        int i = i0 + j;
        if (i < n) { int val = out[i] + add; out[i] = val; out2[i] = val; }
    }
    if (blk == 0 && threadIdx.x == 0) out[n] = bofs[nblk];
}

// ---------------- fused: scatter_tail | scatter_rel | tobf16 | prep(relmap+mkpr) ----------------
__global__ __launch_bounds__(256) void k_scatter_fused(
        const int* __restrict__ heads, const int* __restrict__ tails, const int* __restrict__ types,
        int nE, int num_ent, int num_rel,
        int* __restrict__ tail_cur, u32* __restrict__ tail_edges,
        int* __restrict__ rel_cur, u32* __restrict__ rel_edges,
        const float4* __restrict__ x4, u32* __restrict__ xh, int n4,
        const float* __restrict__ rel_att, const float* __restrict__ r0,
        int* __restrict__ posmap, int* __restrict__ topmap, u32* __restrict__ pr0,
        int nc, int np) {
    int bid = blockIdx.x;
    if (bid < NT) {
        // ---- tail CSR scatter: XCD-partitioned by tail range ----
        int xcd = bid & 7;
        int w = bid >> 3;
        int nw = NT >> 3;
        int per = (num_ent + 7) >> 3;
        int lo = xcd * per, hi = min(lo + per, num_ent);
        for (int i = w * 256 + (int)threadIdx.x; i < nE; i += nw * 256) {
            int t = tails[i];
            if (t >= lo && t < hi) {
                int p = atomicAdd(&tail_cur[t], 1);
                tail_edges[p] = (u32)heads[i] | ((u32)types[i] << 16);
            }
        }
    } else if (bid < NT + NB) {
        // ---- rel CSR scatter: LDS hist -> block reservation -> LDS ranks ----
        __shared__ int hist[NRMAX];
        __shared__ int base[NRMAX];
        int bi = bid - NT;
        int c = (bi & 7) * (NB >> 3) + (bi >> 3);
        int chunk = (nE + NB - 1) / NB;
        int beg = c * chunk, end = min(beg + chunk, nE);
        for (int q = threadIdx.x; q < num_rel; q += 256) hist[q] = 0;
        __syncthreads();
        for (int i = beg + (int)threadIdx.x; i < end; i += 256) atomicAdd(&hist[types[i]], 1);
        __syncthreads();
        for (int q = threadIdx.x; q < num_rel; q += 256) {
            int h = hist[q];
            base[q] = h > 0 ? atomicAdd(&rel_cur[q], h) : 0;
            hist[q] = 0;
        }
        __syncthreads();
        for (int i = beg + (int)threadIdx.x; i < end; i += 256) {
            int q = types[i];
            int rank = atomicAdd(&hist[q], 1);
            rel_edges[base[q] + rank] = (u32)tails[i] | ((u32)heads[i] << 16);
        }
    } else if (bid < NT + NB + nc) {
        // ---- fp32 -> bf16 row mirror ----
        int i = (bid - NT - NB) * 256 + (int)threadIdx.x;
        if (i < n4) {
            float4 v = x4[i];
            ((uint2*)xh)[i] = make_uint2(pack2bf(v.x, v.y), pack2bf(v.z, v.w));
        }
    } else {
        // ---- prep: per-relation top-k permutation + permuted-rel bf16 table ----
        int q = (bid - NT - NB - nc) * 4 + ((int)threadIdx.x >> 6);
        if (q >= num_rel) return;
        int i = threadIdx.x & 63;            // word i covers dims 2i,2i+1 (factor k=i>>3)
        float v[KF]; int idx[KF];
        for (int k = 0; k < KF; ++k) { v[k] = rel_att[q * KF + k]; idx[k] = k; }
        for (int a = 1; a < KF; ++a) {
            float va = v[a]; int ia = idx[a]; int j = a - 1;
            while (j >= 0 && v[j] < va) { v[j + 1] = v[j]; idx[j + 1] = idx[j]; --j; }
            v[j + 1] = va; idx[j + 1] = ia;
        }
        int pos[KF];
        for (int k = 0; k < KF; ++k) pos[k] = -1;
        for (int j = 0; j < TN; ++j) pos[idx[j]] = j;
        if (i < KF) posmap[q * KF + i] = pos[i];
        if (i < TN) topmap[q * TN + i] = idx[i];
        int k = i >> 3;
        int p = pos[k];
        u32 w = 0;
        if (p >= 0) {
            float a = r0[q * 64 + p * SDIM + ((2 * i) & 15)];
            float b = r0[q * 64 + p * SDIM + ((2 * i + 1) & 15)];
            w = pack2bf(a, b);
        }
        pr0[q * 64 + i] = w;
    }
}

// ---------------- rel pass: dual-edge quarter-wave uint4 gathers ----------------
__global__ __launch_bounds__(256) void k_rel_pass(const u32* __restrict__ xh,
                                                  const int* __restrict__ rel_off,
                                                  const u32* __restrict__ rel_edges,
                                                  float* __restrict__ rsum) {
    int bid = blockIdx.x;
    int q = bid >> 3, s = bid & 7;
    int lane = threadIdx.x & 63;
    int qw = lane >> 4, c = lane & 15;      // lane owns dims 8c..8c+7
    int wid = threadIdx.x >> 6;
    int beg = rel_off[q], end = rel_off[q + 1];
    float acc[8] = {0.f, 0.f, 0.f, 0.f, 0.f, 0.f, 0.f, 0.f};
    int g = s * 4 + wid;                    // 32 strips of 64 edges
    for (int b2 = beg + g * 64; b2 < end; b2 += 32 * 64) {
        int m = min(64, end - b2);
        u32 ew = (lane < m) ? rel_edges[b2 + lane] : 0u;
        for (int j = 0; j < m; j += 8) {
            int i0 = j + qw, i1 = j + qw + 4;
            u32 w0 = __shfl(ew, i0, 64);
            u32 w1 = __shfl(ew, i1, 64);
            uint4 ta0 = make_uint4(0,0,0,0), hb0 = make_uint4(0,0,0,0);
            uint4 ta1 = make_uint4(0,0,0,0), hb1 = make_uint4(0,0,0,0);
            if (i0 < m) {
                ta0 = *(const uint4*)(xh + ((size_t)(w0 & 0xFFFFu) << 6) + (c << 2));
                hb0 = *(const uint4*)(xh + ((size_t)(w0 >> 16) << 6) + (c << 2));
            }
            if (i1 < m) {
                ta1 = *(const uint4*)(xh + ((size_t)(w1 & 0xFFFFu) << 6) + (c << 2));
                hb1 = *(const uint4*)(xh + ((size_t)(w1 >> 16) << 6) + (c << 2));
            }
            acc[0] += (lo16(ta0.x) - lo16(hb0.x)) + (lo16(ta1.x) - lo16(hb1.x));
            acc[1] += (hi16(ta0.x) - hi16(hb0.x)) + (hi16(ta1.x) - hi16(hb1.x));
            acc[2] += (lo16(ta0.y) - lo16(hb0.y)) + (lo16(ta1.y) - lo16(hb1.y));
            acc[3] += (hi16(ta0.y) - hi16(hb0.y)) + (hi16(ta1.y) - hi16(hb1.y));
            acc[4] += (lo16(ta0.z) - lo16(hb0.z)) + (lo16(ta1.z) - lo16(hb1.z));
            acc[5] += (hi16(ta0.z) - hi16(hb0.z)) + (hi16(ta1.z) - hi16(hb1.z));
            acc[6] += (lo16(ta0.w) - lo16(hb0.w)) + (lo16(ta1.w) - lo16(hb1.w));
            acc[7] += (hi16(ta0.w) - hi16(hb0.w)) + (hi16(ta1.w) - hi16(hb1.w));
        }
    }
#pragma unroll
    for (int d = 0; d < 8; ++d) {
        acc[d] += __shfl_xor(acc[d], 16, 64);
        acc[d] += __shfl_xor(acc[d], 32, 64);
    }
    __shared__ float prt[4][EMB];
    if (qw == 0) {
#pragma unroll
        for (int d = 0; d < 8; ++d) prt[wid][c * 8 + d] = acc[d];
    }
    __syncthreads();
    int tid = threadIdx.x;
    if (tid < EMB) {
        float v = prt[0][tid] + prt[1][tid] + prt[2][tid] + prt[3][tid];
        atomicAdd(&rsum[(size_t)q * EMB + tid], v);
    }
}

// ---------------- ent pass: dual-edge quarter-wave uint4 gathers ----------------
template <bool OUT_BF16>
__global__ __launch_bounds__(256) void k_ent_pass(const u32* __restrict__ xh, const u32* __restrict__ prh,
                                                  const int* __restrict__ tail_off,
                                                  const u32* __restrict__ tail_edges,
                                                  u32* __restrict__ xout_h, float4* __restrict__ xout_f,
                                                  int num_ent) {
    int wid = threadIdx.x >> 6;
    int t = blockIdx.x * 4 + wid;
    if (t >= num_ent) return;
    int lane = threadIdx.x & 63;
    int qw = lane >> 4, c = lane & 15;
    int beg = tail_off[t], end = tail_off[t + 1];
    int deg = end - beg;
    float acc[8] = {0.f, 0.f, 0.f, 0.f, 0.f, 0.f, 0.f, 0.f};
    for (int b2 = 0; b2 < deg; b2 += 64) {
        int m = min(64, deg - b2);
        u32 ew = (lane < m) ? tail_edges[beg + b2 + lane] : 0u;
        for (int j = 0; j < m; j += 8) {
            int i0 = j + qw, i1 = j + qw + 4;
            u32 w0 = __shfl(ew, i0, 64);
            u32 w1 = __shfl(ew, i1, 64);
            uint4 xr0 = make_uint4(0,0,0,0), pr0 = make_uint4(0,0,0,0);
            uint4 xr1 = make_uint4(0,0,0,0), pr1 = make_uint4(0,0,0,0);
            if (i0 < m) {
                xr0 = *(const uint4*)(xh + ((size_t)(w0 & 0xFFFFu) << 6) + (c << 2));
                pr0 = *(const uint4*)(prh + ((size_t)(w0 >> 16) << 6) + (c << 2));
            }
            if (i1 < m) {
                xr1 = *(const uint4*)(xh + ((size_t)(w1 & 0xFFFFu) << 6) + (c << 2));
                pr1 = *(const uint4*)(prh + ((size_t)(w1 >> 16) << 6) + (c << 2));
            }
            acc[0] += (lo16(xr0.x) + lo16(pr0.x)) + (lo16(xr1.x) + lo16(pr1.x));
            acc[1] += (hi16(xr0.x) + hi16(pr0.x)) + (hi16(xr1.x) + hi16(pr1.x));
            acc[2] += (lo16(xr0.y) + lo16(pr0.y)) + (lo16(xr1.y) + lo16(pr1.y));
            acc[3] += (hi16(xr0.y) + hi16(pr0.y)) + (hi16(xr1.y) + hi16(pr1.y));
            acc[4] += (lo16(xr0.z) + lo16(pr0.z)) + (lo16(xr1.z) + lo16(pr1.z));
            acc[5] += (hi16(xr0.z) + hi16(pr0.z)) + (hi16(xr1.z) + hi16(pr1.z));
            acc[6] += (lo16(xr0.w) + lo16(pr0.w)) + (lo16(xr1.w) + lo16(pr1.w));
            acc[7] += (hi16(xr0.w) + hi16(pr0.w)) + (hi16(xr1.w) + hi16(pr1.w));
        }
    }
#pragma unroll
    for (int d = 0; d < 8; ++d) {
        acc[d] += __shfl_xor(acc[d], 16, 64);
        acc[d] += __shfl_xor(acc[d], 32, 64);
    }
    if (qw == 0) {
        uint4 sw = *(const uint4*)(xh + ((size_t)t << 6) + (c << 2));  // self-loop row
        float s[8] = { lo16(sw.x), hi16(sw.x), lo16(sw.y), hi16(sw.y),
                       lo16(sw.z), hi16(sw.z), lo16(sw.w), hi16(sw.w) };
        float inv = 1.f / (float)(deg + 1);
        float o[8];
#pragma unroll
        for (int d = 0; d < 8; ++d) {
            float v = (acc[d] + s[d]) * inv;
            o[d] = v > 0.f ? v : 0.f;
        }
        if (OUT_BF16) {
            uint4 ow = make_uint4(pack2bf(o[0], o[1]), pack2bf(o[2], o[3]),
                                  pack2bf(o[4], o[5]), pack2bf(o[6], o[7]));
            *(uint4*)(xout_h + ((size_t)t << 6) + (c << 2)) = ow;
        } else {
            xout_f[((size_t)t << 5) + (c << 1)]     = make_float4(o[0], o[1], o[2], o[3]);
            xout_f[((size_t)t << 5) + (c << 1) + 1] = make_float4(o[4], o[5], o[6], o[7]);
        }
    }
}

// ---------------- layer-1 fused: rel mean -> permuted bf16 table ----------------
__global__ __launch_bounds__(64) void k_relfin_pr(const float* __restrict__ rsum,
                                                  const int* __restrict__ rel_off,
                                                  const int* __restrict__ posmap,
                                                  u32* __restrict__ prh, int num_rel) {
    int q = blockIdx.x;
    if (q >= num_rel) return;
    int i = threadIdx.x;
    int k = i >> 3;
    int pos = posmap[q * KF + k];
    int cnt = rel_off[q + 1] - rel_off[q];
    u32 w = 0;
    if (pos >= 0 && cnt > 0) {
        float inv = 1.f / (float)cnt;
        w = pack2bf(rsum[(size_t)q * EMB + 2 * i] * inv, rsum[(size_t)q * EMB + 2 * i + 1] * inv);
    }
    prh[q * 64 + i] = w;
}

// ---------------- rel finalize (layer 2): mean + top-4 gather ----------------
__global__ __launch_bounds__(64) void k_relfin(const float* __restrict__ rsum,
                                               const int* __restrict__ rel_off,
                                               const int* __restrict__ topmap,
                                               float* __restrict__ rout) {
    int q = blockIdx.x;
    int t = threadIdx.x;
    int cnt = rel_off[q + 1] - rel_off[q];
    int j = t >> 4, sd = t & 15;
    int k = topmap[q * TN + j];
    float v = cnt > 0 ? rsum[(size_t)q * EMB + k * SDIM + sd] / (float)cnt : 0.f;
    rout[q * (TN * SDIM) + t] = v;
}

extern "C" void kernel_launch(void* const* d_in, const int* in_sizes, int n_in,
                              void* d_out, int out_size, void* d_ws, size_t ws_size,
                              hipStream_t stream) {
    const float* x0 = (const float*)d_in[0];
    const float* r0 = (const float*)d_in[1];
    const float* rel_att = (const float*)d_in[2];
    const int* edge_index = (const int*)d_in[3];
    const int* edge_type = (const int*)d_in[4];

    const int num_ent = in_sizes[0] / EMB;
    const int num_rel = in_sizes[2] / KF;
    const int nE = in_sizes[4];

    const int* heads = edge_index;
    const int* tails = edge_index + nE;

    const int nblk = (num_ent + SCE - 1) / SCE;
    const int n4 = num_ent * 32;
    const int nc = (n4 + 255) / 256;          // tobf16 blocks
    const int np = (num_rel + 3) / 4;         // prep blocks

    // ---- workspace carve-up ----
    char* base = (char*)d_ws;
    size_t off = 0;
    auto carve = [&](size_t bytes) { char* p = base + off; off = (off + bytes + 255) & ~(size_t)255; return p; };
    int* deg        = (int*)carve((size_t)num_ent * 4);
    int* tail_off   = (int*)carve((size_t)(num_ent + 1) * 4);
    int* tail_cur   = (int*)carve((size_t)num_ent * 4);
    u32* tail_edges = (u32*)carve((size_t)nE * 4);
    int* rcnt       = (int*)carve((size_t)num_rel * 4);
    int* rel_off    = (int*)carve((size_t)(num_rel + 1) * 4);
    int* rel_cur    = (int*)carve((size_t)num_rel * 4);
    u32* rel_edges  = (u32*)carve((size_t)nE * 4);
    int* posmap     = (int*)carve((size_t)num_rel * KF * 4);
    int* topmap     = (int*)carve((size_t)num_rel * TN * 4);
    int* bsum       = (int*)carve((size_t)nblk * 4);
    int* bofs       = (int*)carve((size_t)(nblk + 1) * 4);
    u32* x0h        = (u32*)carve((size_t)num_ent * EMB * 2);
    u32* x1h        = (u32*)carve((size_t)num_ent * EMB * 2);
    u32* pr0        = (u32*)carve((size_t)num_rel * 64 * 4);
    u32* pr1        = (u32*)carve((size_t)num_rel * 64 * 4);
    float* rsumA    = (float*)carve((size_t)num_rel * EMB * 4);
    float* rsumB    = (float*)carve((size_t)num_rel * EMB * 4);
    (void)ws_size;

    float* x_out = (float*)d_out;
    float* r_out = (float*)d_out + (size_t)num_ent * EMB;

    // 1. init
    int initmax = num_ent > num_rel * EMB ? num_ent : num_rel * EMB;
    k_init<<<(initmax + 255) / 256, 256, 0, stream>>>(deg, num_ent, rcnt, num_rel,
                                                      rsumA, rsumB, num_rel * EMB);
    // 2. histograms
    k_hist<<<256, 256, 0, stream>>>(tails, edge_type, nE, num_rel, deg, rcnt);
    // 3-5. scans
    k_scan1<<<nblk, 256, 0, stream>>>(deg, tail_off, bsum, num_ent);
    k_scan_pair<<<2, 1024, 0, stream>>>(bsum, bofs, nblk, rcnt, rel_off, rel_cur, num_rel);
    k_scan2<<<nblk, 256, 0, stream>>>(tail_off, tail_cur, bofs, num_ent, nblk);
    // 6. fused scatters + bf16 mirror + prep
    k_scatter_fused<<<NT + NB + nc + np, 256, 0, stream>>>(
        heads, tails, edge_type, nE, num_ent, num_rel,
        tail_cur, tail_edges, rel_cur, rel_edges,
        (const float4*)x0, x0h, n4, rel_att, r0, posmap, topmap, pr0, nc, np);

    int egrid = (num_ent + 3) / 4;

    // 7-9. layer 1
    k_rel_pass<<<num_rel * NS, 256, 0, stream>>>(x0h, rel_off, rel_edges, rsumA);
    k_ent_pass<true><<<egrid, 256, 0, stream>>>(x0h, pr0, tail_off, tail_edges, x1h, nullptr, num_ent);
    k_relfin_pr<<<num_rel, 64, 0, stream>>>(rsumA, rel_off, posmap, pr1, num_rel);

    // 10-12. layer 2
    k_rel_pass<<<num_rel * NS, 256, 0, stream>>>(x1h, rel_off, rel_edges, rsumB);
    k_ent_pass<false><<<egrid, 256, 0, stream>>>(x1h, pr1, tail_off, tail_edges, nullptr, (float4*)x_out, num_ent);
    k_relfin<<<num_rel, 64, 0, stream>>>(rsumB, rel_off, topmap, r_out);
}

// Round 10
// 195.696 us; speedup vs baseline: 1.1964x; 1.1964x over previous
//
#include <hip/hip_runtime.h>

#define KF 8
#define TN 4
#define SDIM 16
#define EMB 128
#define NS 8     // rel-pass split factor
#define NB 128   // rel-scatter chunk count
#define NT 512   // tail-scatter blocks
#define NRMAX 512
#define SCE 1024 // elements per scan block

typedef unsigned int u32;

// ---- bf16 helpers (manual RNE pack, bit-shift unpack) ----
__device__ __forceinline__ u32 pack2bf(float a, float b) {
    u32 ua = __float_as_uint(a), ub = __float_as_uint(b);
    ua = (ua + 0x7FFFu + ((ua >> 16) & 1u)) >> 16;
    ub = (ub + 0x7FFFu + ((ub >> 16) & 1u)) >> 16;
    return ua | (ub << 16);
}
__device__ __forceinline__ float lo16(u32 w) { return __uint_as_float(w << 16); }
__device__ __forceinline__ float hi16(u32 w) { return __uint_as_float(w & 0xFFFF0000u); }

// ---------------- init: zero deg, rcnt, rsumA, rsumB (top-dims: 64/rel) ----------------
__global__ __launch_bounds__(256) void k_init(int* __restrict__ deg, int num_ent,
                                              int* __restrict__ rcnt, int num_rel,
                                              float* __restrict__ rsumA, float* __restrict__ rsumB,
                                              int nrsum) {
    int i = blockIdx.x * 256 + threadIdx.x;
    if (i < num_ent) deg[i] = 0;
    if (i < num_rel) rcnt[i] = 0;
    if (i < nrsum) { rsumA[i] = 0.f; rsumB[i] = 0.f; }
}

// ---------------- histograms ----------------
__global__ __launch_bounds__(256) void k_hist(const int* __restrict__ tails, const int* __restrict__ types,
                                              int nE, int num_rel,
                                              int* __restrict__ deg, int* __restrict__ rcnt) {
    __shared__ int hist[NRMAX];
    for (int q = threadIdx.x; q < num_rel; q += 256) hist[q] = 0;
    __syncthreads();
    for (int i = blockIdx.x * 256 + threadIdx.x; i < nE; i += gridDim.x * 256) {
        atomicAdd(&deg[tails[i]], 1);
        atomicAdd(&hist[types[i]], 1);
    }
    __syncthreads();
    for (int q = threadIdx.x; q < num_rel; q += 256) {
        int h = hist[q];
        if (h) atomicAdd(&rcnt[q], h);
    }
}

// ---------------- small exclusive scan as device func (one block) ----------------
__device__ void scan_small(const int* __restrict__ in, int* __restrict__ out, int* __restrict__ out2, int n) {
    __shared__ int warp_sums[16];
    int carry = 0;
    int lane = threadIdx.x & 63, wid = threadIdx.x >> 6;
    int nw = blockDim.x >> 6;
    for (int base = 0; base < n; base += blockDim.x) {
        int i = base + (int)threadIdx.x;
        int v = (i < n) ? in[i] : 0;
        int sv = v;
        for (int o = 1; o < 64; o <<= 1) { int t = __shfl_up(sv, o, 64); if (lane >= o) sv += t; }
        if (lane == 63) warp_sums[wid] = sv;
        __syncthreads();
        if (wid == 0 && lane < nw) {
            int ws = warp_sums[lane];
            for (int o = 1; o < 16; o <<= 1) { int t = __shfl_up(ws, o, 64); if (lane >= o) ws += t; }
            warp_sums[lane] = ws;
        }
        __syncthreads();
        int wofs = (wid > 0) ? warp_sums[wid - 1] : 0;
        int total = warp_sums[nw - 1];
        if (i < n) {
            int e = carry + wofs + sv - v;
            out[i] = e;
            if (out2) out2[i] = e;
        }
        carry += total;
        __syncthreads();
    }
    if (threadIdx.x == 0) out[n] = carry;
}

// block 0: bsum->bofs ; block 1: rcnt->rel_off(+rel_cur)
__global__ void k_scan_pair(const int* __restrict__ bsum, int* __restrict__ bofs, int nblk,
                            const int* __restrict__ rcnt, int* __restrict__ rel_off,
                            int* __restrict__ rel_cur, int num_rel) {
    if (blockIdx.x == 0) scan_small(bsum, bofs, nullptr, nblk);
    else                 scan_small(rcnt, rel_off, rel_cur, num_rel);
}

// ---------------- hierarchical scan phase 1 ----------------
__global__ __launch_bounds__(256) void k_scan1(const int* __restrict__ in, int* __restrict__ out,
                                               int* __restrict__ bsum, int n) {
    __shared__ int warp_sums[4];
    int blk = blockIdx.x;
    int i0 = blk * SCE + (int)threadIdx.x * 4;
    int v[4];
#pragma unroll
    for (int j = 0; j < 4; ++j) { int i = i0 + j; v[j] = (i < n) ? in[i] : 0; }
    int tsum = v[0] + v[1] + v[2] + v[3];
    int lane = threadIdx.x & 63, wid = threadIdx.x >> 6;
    int sv = tsum;
    for (int o = 1; o < 64; o <<= 1) { int t = __shfl_up(sv, o, 64); if (lane >= o) sv += t; }
    if (lane == 63) warp_sums[wid] = sv;
    __syncthreads();
    if (threadIdx.x == 0) {
        int s = 0;
        for (int w = 0; w < 4; ++w) { int t = warp_sums[w]; warp_sums[w] = s; s += t; }
        bsum[blk] = s;
    }
    __syncthreads();
    int run = warp_sums[wid] + sv - tsum;
#pragma unroll
    for (int j = 0; j < 4; ++j) { int i = i0 + j; if (i < n) out[i] = run; run += v[j]; }
}

// ---------------- hierarchical scan phase 3 ----------------
__global__ __launch_bounds__(256) void k_scan2(int* __restrict__ out, int* __restrict__ out2,
                                               const int* __restrict__ bofs, int n, int nblk) {
    int blk = blockIdx.x;
    int add = bofs[blk];
    int i0 = blk * SCE + (int)threadIdx.x * 4;
#pragma unroll
    for (int j = 0; j < 4; ++j) {
        int i = i0 + j;
        if (i < n) { int val = out[i] + add; out[i] = val; out2[i] = val; }
    }
    if (blk == 0 && threadIdx.x == 0) out[n] = bofs[nblk];
}

// ---------------- fused: scatter_tail | scatter_rel | tobf16 | prep(relmap+mkpr) ----------------
__global__ __launch_bounds__(256) void k_scatter_fused(
        const int* __restrict__ heads, const int* __restrict__ tails, const int* __restrict__ types,
        int nE, int num_ent, int num_rel,
        int* __restrict__ tail_cur, u32* __restrict__ tail_edges,
        int* __restrict__ rel_cur, u32* __restrict__ rel_edges,
        const float4* __restrict__ x4, u32* __restrict__ xh, int n4,
        const float* __restrict__ rel_att, const float* __restrict__ r0,
        int* __restrict__ posmap, int* __restrict__ topmap, u32* __restrict__ pr0,
        int nc, int np) {
    int bid = blockIdx.x;
    if (bid < NT) {
        // ---- tail CSR scatter: XCD-partitioned by tail range ----
        int xcd = bid & 7;
        int w = bid >> 3;
        int nw = NT >> 3;
        int per = (num_ent + 7) >> 3;
        int lo = xcd * per, hi = min(lo + per, num_ent);
        for (int i = w * 256 + (int)threadIdx.x; i < nE; i += nw * 256) {
            int t = tails[i];
            if (t >= lo && t < hi) {
                int p = atomicAdd(&tail_cur[t], 1);
                tail_edges[p] = (u32)heads[i] | ((u32)types[i] << 16);
            }
        }
    } else if (bid < NT + NB) {
        // ---- rel CSR scatter: LDS hist -> block reservation -> LDS ranks ----
        __shared__ int hist[NRMAX];
        __shared__ int base[NRMAX];
        int bi = bid - NT;
        int c = (bi & 7) * (NB >> 3) + (bi >> 3);
        int chunk = (nE + NB - 1) / NB;
        int beg = c * chunk, end = min(beg + chunk, nE);
        for (int q = threadIdx.x; q < num_rel; q += 256) hist[q] = 0;
        __syncthreads();
        for (int i = beg + (int)threadIdx.x; i < end; i += 256) atomicAdd(&hist[types[i]], 1);
        __syncthreads();
        for (int q = threadIdx.x; q < num_rel; q += 256) {
            int h = hist[q];
            base[q] = h > 0 ? atomicAdd(&rel_cur[q], h) : 0;
            hist[q] = 0;
        }
        __syncthreads();
        for (int i = beg + (int)threadIdx.x; i < end; i += 256) {
            int q = types[i];
            int rank = atomicAdd(&hist[q], 1);
            rel_edges[base[q] + rank] = (u32)tails[i] | ((u32)heads[i] << 16);
        }
    } else if (bid < NT + NB + nc) {
        // ---- fp32 -> bf16 row mirror ----
        int i = (bid - NT - NB) * 256 + (int)threadIdx.x;
        if (i < n4) {
            float4 v = x4[i];
            ((uint2*)xh)[i] = make_uint2(pack2bf(v.x, v.y), pack2bf(v.z, v.w));
        }
    } else {
        // ---- prep: per-relation top-k permutation + permuted-rel bf16 table ----
        int q = (bid - NT - NB - nc) * 4 + ((int)threadIdx.x >> 6);
        if (q >= num_rel) return;
        int i = threadIdx.x & 63;            // word i covers dims 2i,2i+1 (factor k=i>>3)
        float v[KF]; int idx[KF];
        for (int k = 0; k < KF; ++k) { v[k] = rel_att[q * KF + k]; idx[k] = k; }
        for (int a = 1; a < KF; ++a) {
            float va = v[a]; int ia = idx[a]; int j = a - 1;
            while (j >= 0 && v[j] < va) { v[j + 1] = v[j]; idx[j + 1] = idx[j]; --j; }
            v[j + 1] = va; idx[j + 1] = ia;
        }
        int pos[KF];
        for (int k = 0; k < KF; ++k) pos[k] = -1;
        for (int j = 0; j < TN; ++j) pos[idx[j]] = j;
        if (i < KF) posmap[q * KF + i] = pos[i];
        if (i < TN) topmap[q * TN + i] = idx[i];
        int k = i >> 3;
        int p = pos[k];
        u32 w = 0;
        if (p >= 0) {
            float a = r0[q * 64 + p * SDIM + ((2 * i) & 15)];
            float b = r0[q * 64 + p * SDIM + ((2 * i + 1) & 15)];
            w = pack2bf(a, b);
        }
        pr0[q * 64 + i] = w;
    }
}

// ---------------- rel pass: top-dims-only interleaved gathers ----------------
// block = (q, s); wave = 4 × 16-lane groups, each group owns one edge stream.
// Lane c (0..15): top-chunk j=c>>2, word w=c&3 -> reads dims [k*16+4w .. k*16+4w+3]
// of x[t] and x[h] where k = topmap[q][j]. Accumulates in TOP-ORDER (= output order).
__global__ __launch_bounds__(256) void k_rel_pass(const u32* __restrict__ xh,
                                                  const int* __restrict__ rel_off,
                                                  const u32* __restrict__ rel_edges,
                                                  const int* __restrict__ topmap,
                                                  float* __restrict__ rsum_top) {
    int bid = blockIdx.x;
    int q = bid >> 3, s = bid & 7;
    int lane = threadIdx.x & 63;
    int qw = lane >> 4, c = lane & 15;
    int wid = threadIdx.x >> 6;
    int k = topmap[q * TN + (c >> 2)];
    int woff = k * 8 + (c & 3) * 2;          // u32-word offset within 64-word row
    int beg = rel_off[q], end = rel_off[q + 1];
    float acc[4] = {0.f, 0.f, 0.f, 0.f};
    for (int e = beg + s * 16 + wid * 4 + qw; e < end; e += 128) {
        u32 ew = rel_edges[e];
        int t = (int)(ew & 0xFFFFu);
        int h = (int)(ew >> 16);
        uint2 ta = *(const uint2*)(xh + ((size_t)t << 6) + woff);
        uint2 hb = *(const uint2*)(xh + ((size_t)h << 6) + woff);
        acc[0] += lo16(ta.x) - lo16(hb.x);
        acc[1] += hi16(ta.x) - hi16(hb.x);
        acc[2] += lo16(ta.y) - lo16(hb.y);
        acc[3] += hi16(ta.y) - hi16(hb.y);
    }
#pragma unroll
    for (int d = 0; d < 4; ++d) {
        acc[d] += __shfl_xor(acc[d], 16, 64);
        acc[d] += __shfl_xor(acc[d], 32, 64);
    }
    __shared__ float prt[4][64];
    if (qw == 0) {
#pragma unroll
        for (int d = 0; d < 4; ++d) prt[wid][c * 4 + d] = acc[d];
    }
    __syncthreads();
    int tid = threadIdx.x;
    if (tid < 64) {
        float v = prt[0][tid] + prt[1][tid] + prt[2][tid] + prt[3][tid];
        atomicAdd(&rsum_top[(size_t)q * 64 + tid], v);
    }
}

// ---------------- ent pass: quarter-wave uint4 gathers, batched edge prefetch (R6 proven) ----------------
template <bool OUT_BF16>
__global__ __launch_bounds__(256) void k_ent_pass(const u32* __restrict__ xh, const u32* __restrict__ prh,
                                                  const int* __restrict__ tail_off,
                                                  const u32* __restrict__ tail_edges,
                                                  u32* __restrict__ xout_h, float4* __restrict__ xout_f,
                                                  int num_ent) {
    int wid = threadIdx.x >> 6;
    int t = blockIdx.x * 4 + wid;
    if (t >= num_ent) return;
    int lane = threadIdx.x & 63;
    int qw = lane >> 4, c = lane & 15;
    int beg = tail_off[t], end = tail_off[t + 1];
    int deg = end - beg;
    float acc[8] = {0.f, 0.f, 0.f, 0.f, 0.f, 0.f, 0.f, 0.f};
    for (int b2 = 0; b2 < deg; b2 += 64) {
        int m = min(64, deg - b2);
        u32 ew = (lane < m) ? tail_edges[beg + b2 + lane] : 0u;
        for (int j = 0; j < m; j += 4) {
            int idx = j + qw;
            u32 w = __shfl(ew, idx, 64);
            uint4 xr = make_uint4(0, 0, 0, 0), pr = make_uint4(0, 0, 0, 0);
            if (idx < m) {
                int h = (int)(w & 0xFFFFu);
                int q = (int)(w >> 16);
                xr = *(const uint4*)(xh + ((size_t)h << 6) + (c << 2));
                pr = *(const uint4*)(prh + ((size_t)q << 6) + (c << 2));
            }
            acc[0] += lo16(xr.x) + lo16(pr.x);
            acc[1] += hi16(xr.x) + hi16(pr.x);
            acc[2] += lo16(xr.y) + lo16(pr.y);
            acc[3] += hi16(xr.y) + hi16(pr.y);
            acc[4] += lo16(xr.z) + lo16(pr.z);
            acc[5] += hi16(xr.z) + hi16(pr.z);
            acc[6] += lo16(xr.w) + lo16(pr.w);
            acc[7] += hi16(xr.w) + hi16(pr.w);
        }
    }
#pragma unroll
    for (int d = 0; d < 8; ++d) {
        acc[d] += __shfl_xor(acc[d], 16, 64);
        acc[d] += __shfl_xor(acc[d], 32, 64);
    }
    if (qw == 0) {
        uint4 sw = *(const uint4*)(xh + ((size_t)t << 6) + (c << 2));  // self-loop row
        float s[8] = { lo16(sw.x), hi16(sw.x), lo16(sw.y), hi16(sw.y),
                       lo16(sw.z), hi16(sw.z), lo16(sw.w), hi16(sw.w) };
        float inv = 1.f / (float)(deg + 1);
        float o[8];
#pragma unroll
        for (int d = 0; d < 8; ++d) {
            float v = (acc[d] + s[d]) * inv;
            o[d] = v > 0.f ? v : 0.f;
        }
        if (OUT_BF16) {
            uint4 ow = make_uint4(pack2bf(o[0], o[1]), pack2bf(o[2], o[3]),
                                  pack2bf(o[4], o[5]), pack2bf(o[6], o[7]));
            *(uint4*)(xout_h + ((size_t)t << 6) + (c << 2)) = ow;
        } else {
            xout_f[((size_t)t << 5) + (c << 1)]     = make_float4(o[0], o[1], o[2], o[3]);
            xout_f[((size_t)t << 5) + (c << 1) + 1] = make_float4(o[4], o[5], o[6], o[7]);
        }
    }
}

// ---------------- layer-1 fused: rsum_top mean -> permuted bf16 table ----------------
// pr word i covers global dims 2i,2i+1 of factor k=i>>3; in top-order storage factor k
// (if selected) sits at [pos*16 .. pos*16+15].
__global__ __launch_bounds__(64) void k_relfin_pr(const float* __restrict__ rsum_top,
                                                  const int* __restrict__ rel_off,
                                                  const int* __restrict__ posmap,
                                                  u32* __restrict__ prh, int num_rel) {
    int q = blockIdx.x;
    if (q >= num_rel) return;
    int i = threadIdx.x;
    int k = i >> 3;
    int pos = posmap[q * KF + k];
    int cnt = rel_off[q + 1] - rel_off[q];
    u32 w = 0;
    if (pos >= 0 && cnt > 0) {
        float inv = 1.f / (float)cnt;
        int d0 = (2 * i) & 15;
        float a = rsum_top[(size_t)q * 64 + pos * SDIM + d0] * inv;
        float b = rsum_top[(size_t)q * 64 + pos * SDIM + d0 + 1] * inv;
        w = pack2bf(a, b);
    }
    prh[q * 64 + i] = w;
}

// ---------------- rel finalize (layer 2): top-order is output order -> scaled copy ----------------
__global__ __launch_bounds__(64) void k_relfin(const float* __restrict__ rsum_top,
                                               const int* __restrict__ rel_off,
                                               float* __restrict__ rout) {
    int q = blockIdx.x;
    int t = threadIdx.x;
    int cnt = rel_off[q + 1] - rel_off[q];
    rout[q * 64 + t] = cnt > 0 ? rsum_top[(size_t)q * 64 + t] / (float)cnt : 0.f;
}

extern "C" void kernel_launch(void* const* d_in, const int* in_sizes, int n_in,
                              void* d_out, int out_size, void* d_ws, size_t ws_size,
                              hipStream_t stream) {
    const float* x0 = (const float*)d_in[0];
    const float* r0 = (const float*)d_in[1];
    const float* rel_att = (const float*)d_in[2];
    const int* edge_index = (const int*)d_in[3];
    const int* edge_type = (const int*)d_in[4];

    const int num_ent = in_sizes[0] / EMB;
    const int num_rel = in_sizes[2] / KF;
    const int nE = in_sizes[4];

    const int* heads = edge_index;
    const int* tails = edge_index + nE;

    const int nblk = (num_ent + SCE - 1) / SCE;
    const int n4 = num_ent * 32;
    const int nc = (n4 + 255) / 256;          // tobf16 blocks
    const int np = (num_rel + 3) / 4;         // prep blocks

    // ---- workspace carve-up ----
    char* base = (char*)d_ws;
    size_t off = 0;
    auto carve = [&](size_t bytes) { char* p = base + off; off = (off + bytes + 255) & ~(size_t)255; return p; };
    int* deg        = (int*)carve((size_t)num_ent * 4);
    int* tail_off   = (int*)carve((size_t)(num_ent + 1) * 4);
    int* tail_cur   = (int*)carve((size_t)num_ent * 4);
    u32* tail_edges = (u32*)carve((size_t)nE * 4);
    int* rcnt       = (int*)carve((size_t)num_rel * 4);
    int* rel_off    = (int*)carve((size_t)(num_rel + 1) * 4);
    int* rel_cur    = (int*)carve((size_t)num_rel * 4);
    u32* rel_edges  = (u32*)carve((size_t)nE * 4);
    int* posmap     = (int*)carve((size_t)num_rel * KF * 4);
    int* topmap     = (int*)carve((size_t)num_rel * TN * 4);
    int* bsum       = (int*)carve((size_t)nblk * 4);
    int* bofs       = (int*)carve((size_t)(nblk + 1) * 4);
    u32* x0h        = (u32*)carve((size_t)num_ent * EMB * 2);
    u32* x1h        = (u32*)carve((size_t)num_ent * EMB * 2);
    u32* pr0        = (u32*)carve((size_t)num_rel * 64 * 4);
    u32* pr1        = (u32*)carve((size_t)num_rel * 64 * 4);
    float* rsumA    = (float*)carve((size_t)num_rel * 64 * 4);   // top-order sums
    float* rsumB    = (float*)carve((size_t)num_rel * 64 * 4);
    (void)ws_size;

    float* x_out = (float*)d_out;
    float* r_out = (float*)d_out + (size_t)num_ent * EMB;

    // 1. init
    int initmax = num_ent > num_rel * 64 ? num_ent : num_rel * 64;
    k_init<<<(initmax + 255) / 256, 256, 0, stream>>>(deg, num_ent, rcnt, num_rel,
                                                      rsumA, rsumB, num_rel * 64);
    // 2. histograms
    k_hist<<<256, 256, 0, stream>>>(tails, edge_type, nE, num_rel, deg, rcnt);
    // 3-5. scans
    k_scan1<<<nblk, 256, 0, stream>>>(deg, tail_off, bsum, num_ent);
    k_scan_pair<<<2, 1024, 0, stream>>>(bsum, bofs, nblk, rcnt, rel_off, rel_cur, num_rel);
    k_scan2<<<nblk, 256, 0, stream>>>(tail_off, tail_cur, bofs, num_ent, nblk);
    // 6. fused scatters + bf16 mirror + prep
    k_scatter_fused<<<NT + NB + nc + np, 256, 0, stream>>>(
        heads, tails, edge_type, nE, num_ent, num_rel,
        tail_cur, tail_edges, rel_cur, rel_edges,
        (const float4*)x0, x0h, n4, rel_att, r0, posmap, topmap, pr0, nc, np);

    int egrid = (num_ent + 3) / 4;

    // 7-9. layer 1
    k_rel_pass<<<num_rel * NS, 256, 0, stream>>>(x0h, rel_off, rel_edges, topmap, rsumA);
    k_ent_pass<true><<<egrid, 256, 0, stream>>>(x0h, pr0, tail_off, tail_edges, x1h, nullptr, num_ent);
    k_relfin_pr<<<num_rel, 64, 0, stream>>>(rsumA, rel_off, posmap, pr1, num_rel);

    // 10-12. layer 2
    k_rel_pass<<<num_rel * NS, 256, 0, stream>>>(x1h, rel_off, rel_edges, topmap, rsumB);
    k_ent_pass<false><<<egrid, 256, 0, stream>>>(x1h, pr1, tail_off, tail_edges, nullptr, (float4*)x_out, num_ent);
    k_relfin<<<num_rel, 64, 0, stream>>>(rsumB, rel_off, r_out);
}

// Round 11
// 189.743 us; speedup vs baseline: 1.2339x; 1.0314x over previous
//
#include <hip/hip_runtime.h>

#define KF 8
#define TN 4
#define SDIM 16
#define EMB 128
#define NS 8     // rel-pass split factor
#define NB 128   // rel-scatter chunk count
#define NT 512   // tail-scatter blocks
#define NRMAX 512
#define SCE 1024 // elements per scan block

typedef unsigned int u32;

// ---- bf16 helpers (manual RNE pack, bit-shift unpack) ----
__device__ __forceinline__ u32 pack2bf(float a, float b) {
    u32 ua = __float_as_uint(a), ub = __float_as_uint(b);
    ua = (ua + 0x7FFFu + ((ua >> 16) & 1u)) >> 16;
    ub = (ub + 0x7FFFu + ((ub >> 16) & 1u)) >> 16;
    return ua | (ub << 16);
}
__device__ __forceinline__ float lo16(u32 w) { return __uint_as_float(w << 16); }
__device__ __forceinline__ float hi16(u32 w) { return __uint_as_float(w & 0xFFFF0000u); }

// ---------------- init: zero deg, rcnt, rsumA, rsumB, scan flags ----------------
__global__ __launch_bounds__(256) void k_init(int* __restrict__ deg, int num_ent,
                                              int* __restrict__ rcnt, int num_rel,
                                              float* __restrict__ rsumA, float* __restrict__ rsumB,
                                              int nrsum, int* __restrict__ flags, int nblk) {
    int i = blockIdx.x * 256 + threadIdx.x;
    if (i < num_ent) deg[i] = 0;
    if (i < num_rel) rcnt[i] = 0;
    if (i < nrsum) { rsumA[i] = 0.f; rsumB[i] = 0.f; }
    if (i < nblk) flags[i] = 0;
}

// ---------------- histograms ----------------
__global__ __launch_bounds__(256) void k_hist(const int* __restrict__ tails, const int* __restrict__ types,
                                              int nE, int num_rel,
                                              int* __restrict__ deg, int* __restrict__ rcnt) {
    __shared__ int hist[NRMAX];
    for (int q = threadIdx.x; q < num_rel; q += 256) hist[q] = 0;
    __syncthreads();
    for (int i = blockIdx.x * 256 + threadIdx.x; i < nE; i += gridDim.x * 256) {
        atomicAdd(&deg[tails[i]], 1);
        atomicAdd(&hist[types[i]], 1);
    }
    __syncthreads();
    for (int q = threadIdx.x; q < num_rel; q += 256) {
        int h = hist[q];
        if (h) atomicAdd(&rcnt[q], h);
    }
}

// ---------------- small exclusive scan as device func (one block) ----------------
__device__ void scan_small(const int* __restrict__ in, int* __restrict__ out, int* __restrict__ out2, int n) {
    __shared__ int warp_sums[16];
    int carry = 0;
    int lane = threadIdx.x & 63, wid = threadIdx.x >> 6;
    int nw = blockDim.x >> 6;
    for (int base = 0; base < n; base += blockDim.x) {
        int i = base + (int)threadIdx.x;
        int v = (i < n) ? in[i] : 0;
        int sv = v;
        for (int o = 1; o < 64; o <<= 1) { int t = __shfl_up(sv, o, 64); if (lane >= o) sv += t; }
        if (lane == 63) warp_sums[wid] = sv;
        __syncthreads();
        if (wid == 0 && lane < nw) {
            int ws = warp_sums[lane];
            for (int o = 1; o < 16; o <<= 1) { int t = __shfl_up(ws, o, 64); if (lane >= o) ws += t; }
            warp_sums[lane] = ws;
        }
        __syncthreads();
        int wofs = (wid > 0) ? warp_sums[wid - 1] : 0;
        int total = warp_sums[nw - 1];
        if (i < n) {
            int e = carry + wofs + sv - v;
            out[i] = e;
            if (out2) out2[i] = e;
        }
        carry += total;
        __syncthreads();
    }
    if (threadIdx.x == 0) out[n] = carry;
}

// ---------------- fused scan: blocks 0..nblk-1 lookback-scan deg; block nblk scans rcnt ----------------
__global__ __launch_bounds__(256) void k_scan_fused(const int* __restrict__ deg,
                                                    int* __restrict__ tail_off, int* __restrict__ tail_cur,
                                                    int n, int nblk,
                                                    int* __restrict__ vals, int* __restrict__ flags,
                                                    const int* __restrict__ rcnt, int* __restrict__ rel_off,
                                                    int* __restrict__ rel_cur, int num_rel) {
    int b = blockIdx.x;
    if (b == nblk) { scan_small(rcnt, rel_off, rel_cur, num_rel); return; }
    __shared__ int wsum[4];
    __shared__ int pw[4];
    __shared__ int sprefix;
    int tid = threadIdx.x;
    int lane = tid & 63, wid = tid >> 6;
    int i0 = b * SCE + tid * 4;
    int v[4];
#pragma unroll
    for (int j = 0; j < 4; ++j) { int i = i0 + j; v[j] = (i < n) ? deg[i] : 0; }
    int tsum = v[0] + v[1] + v[2] + v[3];
    int sv = tsum;
    for (int o = 1; o < 64; o <<= 1) { int t = __shfl_up(sv, o, 64); if (lane >= o) sv += t; }
    if (lane == 63) wsum[wid] = sv;
    __syncthreads();
    if (tid == 0) {
        int s = 0;
        for (int w = 0; w < 4; ++w) { int t = wsum[w]; wsum[w] = s; s += t; }
        vals[b] = s;
        __threadfence();
        atomicExch(&flags[b], 1);     // publish block aggregate
    }
    __syncthreads();
    // parallel lookback over predecessors
    int p = 0;
    for (int i = tid; i < b; i += 256) {
        while (atomicAdd(&flags[i], 0) == 0) {}
        p += atomicAdd(&vals[i], 0);  // atomic read avoids stale L1
    }
    for (int o = 1; o < 64; o <<= 1) p += __shfl_xor(p, o, 64);
    if (lane == 0) pw[wid] = p;
    __syncthreads();
    if (tid == 0) sprefix = pw[0] + pw[1] + pw[2] + pw[3];
    __syncthreads();
    int run = sprefix + wsum[wid] + (sv - tsum);
#pragma unroll
    for (int j = 0; j < 4; ++j) {
        int i = i0 + j;
        if (i < n) { tail_off[i] = run; tail_cur[i] = run; }
        run += v[j];
    }
    if (b == nblk - 1 && tid == 0) tail_off[n] = sprefix + vals[b];
}

// ---------------- fused: scatter_tail | scatter_rel | tobf16 | prep(relmap+mkpr) ----------------
__global__ __launch_bounds__(256) void k_scatter_fused(
        const int* __restrict__ heads, const int* __restrict__ tails, const int* __restrict__ types,
        int nE, int num_ent, int num_rel,
        int* __restrict__ tail_cur, u32* __restrict__ tail_edges,
        int* __restrict__ rel_cur, u32* __restrict__ rel_edges,
        const float4* __restrict__ x4, u32* __restrict__ xh, int n4,
        const float* __restrict__ rel_att, const float* __restrict__ r0,
        int* __restrict__ posmap, int* __restrict__ topmap, u32* __restrict__ pr0,
        int nc, int np) {
    int bid = blockIdx.x;
    if (bid < NT) {
        // ---- tail CSR scatter: XCD-partitioned by tail range ----
        int xcd = bid & 7;
        int w = bid >> 3;
        int nw = NT >> 3;
        int per = (num_ent + 7) >> 3;
        int lo = xcd * per, hi = min(lo + per, num_ent);
        for (int i = w * 256 + (int)threadIdx.x; i < nE; i += nw * 256) {
            int t = tails[i];
            if (t >= lo && t < hi) {
                int p = atomicAdd(&tail_cur[t], 1);
                tail_edges[p] = (u32)heads[i] | ((u32)types[i] << 16);
            }
        }
    } else if (bid < NT + NB) {
        // ---- rel CSR scatter: LDS hist -> block reservation -> LDS ranks ----
        __shared__ int hist[NRMAX];
        __shared__ int base[NRMAX];
        int bi = bid - NT;
        int c = (bi & 7) * (NB >> 3) + (bi >> 3);
        int chunk = (nE + NB - 1) / NB;
        int beg = c * chunk, end = min(beg + chunk, nE);
        for (int q = threadIdx.x; q < num_rel; q += 256) hist[q] = 0;
        __syncthreads();
        for (int i = beg + (int)threadIdx.x; i < end; i += 256) atomicAdd(&hist[types[i]], 1);
        __syncthreads();
        for (int q = threadIdx.x; q < num_rel; q += 256) {
            int h = hist[q];
            base[q] = h > 0 ? atomicAdd(&rel_cur[q], h) : 0;
            hist[q] = 0;
        }
        __syncthreads();
        for (int i = beg + (int)threadIdx.x; i < end; i += 256) {
            int q = types[i];
            int rank = atomicAdd(&hist[q], 1);
            rel_edges[base[q] + rank] = (u32)tails[i] | ((u32)heads[i] << 16);
        }
    } else if (bid < NT + NB + nc) {
        // ---- fp32 -> bf16 row mirror ----
        int i = (bid - NT - NB) * 256 + (int)threadIdx.x;
        if (i < n4) {
            float4 v = x4[i];
            ((uint2*)xh)[i] = make_uint2(pack2bf(v.x, v.y), pack2bf(v.z, v.w));
        }
    } else {
        // ---- prep: per-relation top-k permutation + permuted-rel bf16 table ----
        int q = (bid - NT - NB - nc) * 4 + ((int)threadIdx.x >> 6);
        if (q >= num_rel) return;
        int i = threadIdx.x & 63;            // word i covers dims 2i,2i+1 (factor k=i>>3)
        float v[KF]; int idx[KF];
        for (int k = 0; k < KF; ++k) { v[k] = rel_att[q * KF + k]; idx[k] = k; }
        for (int a = 1; a < KF; ++a) {
            float va = v[a]; int ia = idx[a]; int j = a - 1;
            while (j >= 0 && v[j] < va) { v[j + 1] = v[j]; idx[j + 1] = idx[j]; --j; }
            v[j + 1] = va; idx[j + 1] = ia;
        }
        int pos[KF];
        for (int k = 0; k < KF; ++k) pos[k] = -1;
        for (int j = 0; j < TN; ++j) pos[idx[j]] = j;
        if (i < KF) posmap[q * KF + i] = pos[i];
        if (i < TN) topmap[q * TN + i] = idx[i];
        int k = i >> 3;
        int p = pos[k];
        u32 w = 0;
        if (p >= 0) {
            float a = r0[q * 64 + p * SDIM + ((2 * i) & 15)];
            float b = r0[q * 64 + p * SDIM + ((2 * i + 1) & 15)];
            w = pack2bf(a, b);
        }
        pr0[q * 64 + i] = w;
    }
}

// ---------------- rel pass: top-dims-only interleaved gathers (R9 proven) ----------------
__global__ __launch_bounds__(256) void k_rel_pass(const u32* __restrict__ xh,
                                                  const int* __restrict__ rel_off,
                                                  const u32* __restrict__ rel_edges,
                                                  const int* __restrict__ topmap,
                                                  float* __restrict__ rsum_top) {
    int bid = blockIdx.x;
    int q = bid >> 3, s = bid & 7;
    int lane = threadIdx.x & 63;
    int qw = lane >> 4, c = lane & 15;
    int wid = threadIdx.x >> 6;
    int k = topmap[q * TN + (c >> 2)];
    int woff = k * 8 + (c & 3) * 2;          // u32-word offset within 64-word row
    int beg = rel_off[q], end = rel_off[q + 1];
    float acc[4] = {0.f, 0.f, 0.f, 0.f};
    for (int e = beg + s * 16 + wid * 4 + qw; e < end; e += 128) {
        u32 ew = rel_edges[e];
        int t = (int)(ew & 0xFFFFu);
        int h = (int)(ew >> 16);
        uint2 ta = *(const uint2*)(xh + ((size_t)t << 6) + woff);
        uint2 hb = *(const uint2*)(xh + ((size_t)h << 6) + woff);
        acc[0] += lo16(ta.x) - lo16(hb.x);
        acc[1] += hi16(ta.x) - hi16(hb.x);
        acc[2] += lo16(ta.y) - lo16(hb.y);
        acc[3] += hi16(ta.y) - hi16(hb.y);
    }
#pragma unroll
    for (int d = 0; d < 4; ++d) {
        acc[d] += __shfl_xor(acc[d], 16, 64);
        acc[d] += __shfl_xor(acc[d], 32, 64);
    }
    __shared__ float prt[4][64];
    if (qw == 0) {
#pragma unroll
        for (int d = 0; d < 4; ++d) prt[wid][c * 4 + d] = acc[d];
    }
    __syncthreads();
    int tid = threadIdx.x;
    if (tid < 64) {
        float v = prt[0][tid] + prt[1][tid] + prt[2][tid] + prt[3][tid];
        atomicAdd(&rsum_top[(size_t)q * 64 + tid], v);
    }
}

// ---------------- ent pass + folded rel-finalize tail blocks ----------------
// blocks [0, egrid): ent gather (R6 proven structure)
// blocks [egrid, ...): OUT_BF16 -> relfin_pr (rsum->pr table); else relfin (rsum->rout)
template <bool OUT_BF16>
__global__ __launch_bounds__(256) void k_ent_pass(const u32* __restrict__ xh, const u32* __restrict__ prh,
                                                  const int* __restrict__ tail_off,
                                                  const u32* __restrict__ tail_edges,
                                                  u32* __restrict__ xout_h, float4* __restrict__ xout_f,
                                                  int num_ent, int egrid,
                                                  const float* __restrict__ rsum_top,
                                                  const int* __restrict__ rel_off,
                                                  const int* __restrict__ posmap,
                                                  u32* __restrict__ pr_out, float* __restrict__ rout,
                                                  int num_rel) {
    int bid = blockIdx.x;
    if (bid >= egrid) {
        if (OUT_BF16) {
            // layer-1 finalize: rsum_top mean -> permuted bf16 table (permutation cancels)
            int q = (bid - egrid) * 4 + ((int)threadIdx.x >> 6);
            if (q >= num_rel) return;
            int i = threadIdx.x & 63;
            int k = i >> 3;
            int pos = posmap[q * KF + k];
            int cnt = rel_off[q + 1] - rel_off[q];
            u32 w = 0;
            if (pos >= 0 && cnt > 0) {
                float inv = 1.f / (float)cnt;
                int d0 = (2 * i) & 15;
                float a = rsum_top[(size_t)q * 64 + pos * SDIM + d0] * inv;
                float b = rsum_top[(size_t)q * 64 + pos * SDIM + d0 + 1] * inv;
                w = pack2bf(a, b);
            }
            pr_out[q * 64 + i] = w;
        } else {
            // layer-2 finalize: top-order is output order -> scaled copy
            int idx = (bid - egrid) * 256 + (int)threadIdx.x;
            if (idx < num_rel * 64) {
                int q = idx >> 6;
                int cnt = rel_off[q + 1] - rel_off[q];
                rout[idx] = cnt > 0 ? rsum_top[idx] / (float)cnt : 0.f;
            }
        }
        return;
    }
    int wid = threadIdx.x >> 6;
    int t = bid * 4 + wid;
    if (t >= num_ent) return;
    int lane = threadIdx.x & 63;
    int qw = lane >> 4, c = lane & 15;
    int beg = tail_off[t], end = tail_off[t + 1];
    int deg = end - beg;
    float acc[8] = {0.f, 0.f, 0.f, 0.f, 0.f, 0.f, 0.f, 0.f};
    for (int b2 = 0; b2 < deg; b2 += 64) {
        int m = min(64, deg - b2);
        u32 ew = (lane < m) ? tail_edges[beg + b2 + lane] : 0u;
        for (int j = 0; j < m; j += 4) {
            int idx = j + qw;
            u32 w = __shfl(ew, idx, 64);
            uint4 xr = make_uint4(0, 0, 0, 0), pr = make_uint4(0, 0, 0, 0);
            if (idx < m) {
                int h = (int)(w & 0xFFFFu);
                int q = (int)(w >> 16);
                xr = *(const uint4*)(xh + ((size_t)h << 6) + (c << 2));
                pr = *(const uint4*)(prh + ((size_t)q << 6) + (c << 2));
            }
            acc[0] += lo16(xr.x) + lo16(pr.x);
            acc[1] += hi16(xr.x) + hi16(pr.x);
            acc[2] += lo16(xr.y) + lo16(pr.y);
            acc[3] += hi16(xr.y) + hi16(pr.y);
            acc[4] += lo16(xr.z) + lo16(pr.z);
            acc[5] += hi16(xr.z) + hi16(pr.z);
            acc[6] += lo16(xr.w) + lo16(pr.w);
            acc[7] += hi16(xr.w) + hi16(pr.w);
        }
    }
#pragma unroll
    for (int d = 0; d < 8; ++d) {
        acc[d] += __shfl_xor(acc[d], 16, 64);
        acc[d] += __shfl_xor(acc[d], 32, 64);
    }
    if (qw == 0) {
        uint4 sw = *(const uint4*)(xh + ((size_t)t << 6) + (c << 2));  // self-loop row
        float s[8] = { lo16(sw.x), hi16(sw.x), lo16(sw.y), hi16(sw.y),
                       lo16(sw.z), hi16(sw.z), lo16(sw.w), hi16(sw.w) };
        float inv = 1.f / (float)(deg + 1);
        float o[8];
#pragma unroll
        for (int d = 0; d < 8; ++d) {
            float v = (acc[d] + s[d]) * inv;
            o[d] = v > 0.f ? v : 0.f;
        }
        if (OUT_BF16) {
            uint4 ow = make_uint4(pack2bf(o[0], o[1]), pack2bf(o[2], o[3]),
                                  pack2bf(o[4], o[5]), pack2bf(o[6], o[7]));
            *(uint4*)(xout_h + ((size_t)t << 6) + (c << 2)) = ow;
        } else {
            xout_f[((size_t)t << 5) + (c << 1)]     = make_float4(o[0], o[1], o[2], o[3]);
            xout_f[((size_t)t << 5) + (c << 1) + 1] = make_float4(o[4], o[5], o[6], o[7]);
        }
    }
}

extern "C" void kernel_launch(void* const* d_in, const int* in_sizes, int n_in,
                              void* d_out, int out_size, void* d_ws, size_t ws_size,
                              hipStream_t stream) {
    const float* x0 = (const float*)d_in[0];
    const float* r0 = (const float*)d_in[1];
    const float* rel_att = (const float*)d_in[2];
    const int* edge_index = (const int*)d_in[3];
    const int* edge_type = (const int*)d_in[4];

    const int num_ent = in_sizes[0] / EMB;
    const int num_rel = in_sizes[2] / KF;
    const int nE = in_sizes[4];

    const int* heads = edge_index;
    const int* tails = edge_index + nE;

    const int nblk = (num_ent + SCE - 1) / SCE;
    const int n4 = num_ent * 32;
    const int nc = (n4 + 255) / 256;          // tobf16 blocks
    const int np = (num_rel + 3) / 4;         // prep blocks

    // ---- workspace carve-up ----
    char* base = (char*)d_ws;
    size_t off = 0;
    auto carve = [&](size_t bytes) { char* p = base + off; off = (off + bytes + 255) & ~(size_t)255; return p; };
    int* deg        = (int*)carve((size_t)num_ent * 4);
    int* tail_off   = (int*)carve((size_t)(num_ent + 1) * 4);
    int* tail_cur   = (int*)carve((size_t)num_ent * 4);
    u32* tail_edges = (u32*)carve((size_t)nE * 4);
    int* rcnt       = (int*)carve((size_t)num_rel * 4);
    int* rel_off    = (int*)carve((size_t)(num_rel + 1) * 4);
    int* rel_cur    = (int*)carve((size_t)num_rel * 4);
    u32* rel_edges  = (u32*)carve((size_t)nE * 4);
    int* posmap     = (int*)carve((size_t)num_rel * KF * 4);
    int* topmap     = (int*)carve((size_t)num_rel * TN * 4);
    int* svals      = (int*)carve((size_t)nblk * 4);
    int* sflags     = (int*)carve((size_t)nblk * 4);
    u32* x0h        = (u32*)carve((size_t)num_ent * EMB * 2);
    u32* x1h        = (u32*)carve((size_t)num_ent * EMB * 2);
    u32* pr0        = (u32*)carve((size_t)num_rel * 64 * 4);
    u32* pr1        = (u32*)carve((size_t)num_rel * 64 * 4);
    float* rsumA    = (float*)carve((size_t)num_rel * 64 * 4);   // top-order sums
    float* rsumB    = (float*)carve((size_t)num_rel * 64 * 4);
    (void)ws_size;

    float* x_out = (float*)d_out;
    float* r_out = (float*)d_out + (size_t)num_ent * EMB;

    // 1. init (zeros deg/rcnt/rsums/scan flags each call — graph-replay safe)
    int initmax = num_ent > num_rel * 64 ? num_ent : num_rel * 64;
    k_init<<<(initmax + 255) / 256, 256, 0, stream>>>(deg, num_ent, rcnt, num_rel,
                                                      rsumA, rsumB, num_rel * 64, sflags, nblk);
    // 2. histograms
    k_hist<<<256, 256, 0, stream>>>(tails, edge_type, nE, num_rel, deg, rcnt);
    // 3. fused lookback scan (deg->tail_off/cur) + rcnt scan
    k_scan_fused<<<nblk + 1, 256, 0, stream>>>(deg, tail_off, tail_cur, num_ent, nblk,
                                               svals, sflags, rcnt, rel_off, rel_cur, num_rel);
    // 4. fused scatters + bf16 mirror + prep
    k_scatter_fused<<<NT + NB + nc + np, 256, 0, stream>>>(
        heads, tails, edge_type, nE, num_ent, num_rel,
        tail_cur, tail_edges, rel_cur, rel_edges,
        (const float4*)x0, x0h, n4, rel_att, r0, posmap, topmap, pr0, nc, np);

    int egrid = (num_ent + 3) / 4;
    int nfin1 = (num_rel + 3) / 4;             // L1 folded relfin_pr blocks
    int nfin2 = (num_rel * 64 + 255) / 256;    // L2 folded relfin blocks

    // 5-6. layer 1
    k_rel_pass<<<num_rel * NS, 256, 0, stream>>>(x0h, rel_off, rel_edges, topmap, rsumA);
    k_ent_pass<true><<<egrid + nfin1, 256, 0, stream>>>(x0h, pr0, tail_off, tail_edges,
                                                        x1h, nullptr, num_ent, egrid,
                                                        rsumA, rel_off, posmap, pr1, nullptr, num_rel);
    // 7-8. layer 2
    k_rel_pass<<<num_rel * NS, 256, 0, stream>>>(x1h, rel_off, rel_edges, topmap, rsumB);
    k_ent_pass<false><<<egrid + nfin2, 256, 0, stream>>>(x1h, pr1, tail_off, tail_edges,
                                                         nullptr, (float4*)x_out, num_ent, egrid,
                                                         rsumB, rel_off, nullptr, nullptr, r_out, num_rel);
}